// Round 19
// baseline (220.683 us; speedup 1.0000x reference)
//
#include <hip/hip_runtime.h>
#include <hip/hip_bf16.h>
#include <stdint.h>

typedef unsigned short u16;
typedef __attribute__((ext_vector_type(8))) short short8;
typedef __attribute__((ext_vector_type(4))) short short4v;
typedef __attribute__((ext_vector_type(4))) float f32x4;

#define MFMA16 __builtin_amdgcn_mfma_f32_16x16x32_bf16

#define GLOAD_LDS16(gsrc, ldst) \
  __builtin_amdgcn_global_load_lds((const __attribute__((address_space(1))) void*)(gsrc), \
                                   (__attribute__((address_space(3))) void*)(ldst), 16, 0, 0)

__device__ __forceinline__ u16 f2bf(float x) {
  union { float f; uint32_t u; } v; v.f = x;
  uint32_t r = v.u + 0x7FFFu + ((v.u >> 16) & 1u);
  return (u16)(r >> 16);
}
__device__ __forceinline__ u16 f2bf_rn(float x) {
  __hip_bfloat16 h = __float2bfloat16(x);
  return *reinterpret_cast<u16*>(&h);
}
__device__ __forceinline__ float bf2f(u16 b) {
  union { uint32_t u; float f; } v; v.u = ((uint32_t)b) << 16;
  return v.f;
}

// ---------------- convert f32 -> bf16 (elementwise, vectorized) ----------------
__global__ __launch_bounds__(256) void convert_bf16_kernel(
    const float* __restrict__ in, u16* __restrict__ out, int n) {
  int i = (blockIdx.x * 256 + threadIdx.x) * 8;
  if (i >= n) return;
  float4 a = *(const float4*)(in + i);
  float4 b = *(const float4*)(in + i + 4);
  short8 t;
  t[0] = (short)f2bf(a.x); t[1] = (short)f2bf(a.y);
  t[2] = (short)f2bf(a.z); t[3] = (short)f2bf(a.w);
  t[4] = (short)f2bf(b.x); t[5] = (short)f2bf(b.y);
  t[6] = (short)f2bf(b.z); t[7] = (short)f2bf(b.w);
  *(short8*)(out + i) = t;
}

// ---------------- transpose 4 weights f32 [K][N] -> bf16 [N][K], z selects W ----------------
__global__ __launch_bounds__(256) void transpose_w64_4(
    const float* __restrict__ w0, const float* __restrict__ w1,
    const float* __restrict__ w2, const float* __restrict__ w3,
    u16* __restrict__ WT) {
  __shared__ float tile[64][68];
  const int t = threadIdx.x;
  const int z = blockIdx.z;
  const float* W = (z == 0) ? w0 : (z == 1) ? w1 : (z == 2) ? w2 : w3;
  u16* dst_base = WT + (size_t)z * 1024 * 1024;
  const int k0 = blockIdx.x * 64, n0 = blockIdx.y * 64;
  {
    int r = t >> 2, c0 = (t & 3) * 16;
    const float* src = W + (size_t)(k0 + r) * 1024 + n0 + c0;
#pragma unroll
    for (int j = 0; j < 16; j += 4) {
      float4 v = *(const float4*)(src + j);
      tile[r][c0 + j + 0] = v.x; tile[r][c0 + j + 1] = v.y;
      tile[r][c0 + j + 2] = v.z; tile[r][c0 + j + 3] = v.w;
    }
  }
  __syncthreads();
  {
    int n = t >> 2, kq = (t & 3) * 16;
    short8 t0, t1;
#pragma unroll
    for (int j = 0; j < 8; ++j)  t0[j] = (short)f2bf(tile[kq + j][n]);
#pragma unroll
    for (int j = 0; j < 8; ++j)  t1[j] = (short)f2bf(tile[kq + 8 + j][n]);
    u16* dst = dst_base + (size_t)(n0 + n) * 1024 + k0 + kq;
    *(short8*)dst = t0;
    *(short8*)(dst + 8) = t1;
  }
}

// ---------------- transpose f32 [K][N] -> bf16 [N][K] (64x64 tiles) ----------------
__global__ __launch_bounds__(256) void transpose_w64(
    const float* __restrict__ W, u16* __restrict__ WT, int KK, int NN) {
  __shared__ float tile[64][68];
  const int t = threadIdx.x;
  const int k0 = blockIdx.x * 64, n0 = blockIdx.y * 64;
  {
    int r = t >> 2, c0 = (t & 3) * 16;
    const float* src = W + (size_t)(k0 + r) * NN + n0 + c0;
#pragma unroll
    for (int j = 0; j < 16; j += 4) {
      float4 v = *(const float4*)(src + j);
      tile[r][c0 + j + 0] = v.x; tile[r][c0 + j + 1] = v.y;
      tile[r][c0 + j + 2] = v.z; tile[r][c0 + j + 3] = v.w;
    }
  }
  __syncthreads();
  {
    int n = t >> 2, kq = (t & 3) * 16;
    short8 t0, t1;
#pragma unroll
    for (int j = 0; j < 8; ++j)  t0[j] = (short)f2bf(tile[kq + j][n]);
#pragma unroll
    for (int j = 0; j < 8; ++j)  t1[j] = (short)f2bf(tile[kq + 8 + j][n]);
    u16* dst = WT + (size_t)(n0 + n) * KK + k0 + kq;
    *(short8*)dst = t0;
    *(short8*)(dst + 8) = t1;
  }
}

// ---------------- transpose V bf16 [b*2048+s][h*64+c] -> VT [(b*16+h)*64+c][s] ----------------
__global__ __launch_bounds__(256) void transpose_v64(
    const u16* __restrict__ vin, u16* __restrict__ vout) {
  __shared__ u16 tile[64][80];
  const int t = threadIdx.x;
  const int s0 = blockIdx.x * 64;
  const int bh = blockIdx.y;  // b*16+h
  const int b = bh >> 4, h = bh & 15;
  {
    int r = t >> 2, c0 = (t & 3) * 16;
    const u16* src = vin + (size_t)(b * 2048 + s0 + r) * 1024 + h * 64 + c0;
    *(short8*)&tile[r][c0] = *(const short8*)src;
    *(short8*)&tile[r][c0 + 8] = *(const short8*)(src + 8);
  }
  __syncthreads();
  {
    int c = t >> 2, s4 = (t & 3) * 16;
    short8 t0, t1;
#pragma unroll
    for (int j = 0; j < 8; ++j) t0[j] = (short)tile[s4 + j][c];
#pragma unroll
    for (int j = 0; j < 8; ++j) t1[j] = (short)tile[s4 + 8 + j][c];
    u16* dst = vout + (size_t)(bh * 64 + c) * 2048 + s0 + s4;
    *(short8*)dst = t0;
    *(short8*)(dst + 8) = t1;
  }
}

// ---------------- GEMM: D[r][n] = sum_k A[r][k]*BT[n][k], m97-style 128x128/BK=64 ----------------
__global__ __launch_bounds__(256) void gemm_bt128(
    const u16* __restrict__ A, const u16* __restrict__ BTbase,
    void* __restrict__ dstbase, const float* __restrict__ bvec, int mode) {
  const int K = 1024;
  const int tid = threadIdx.x, lane = tid & 63, w = tid >> 6;
  const int wr = w >> 1, wc = w & 1;
  const int l15 = lane & 15, lg = lane >> 4;
  const int z = (mode < 0) ? (int)blockIdx.z : mode;
  const u16* BT = (mode < 0) ? BTbase + (size_t)z * 1024 * 1024 : BTbase;
  const int rbase = blockIdx.x * 128;
  const int nbase = blockIdx.y * 128;
  __shared__ u16 lsA[128 * 64];
  __shared__ u16 lsB[128 * 64];
  f32x4 acc[4][4] = {};
  const int col8 = (lane & 7) * 8;
  for (int kt = 0; kt < K / 64; ++kt) {
#pragma unroll
    for (int i = 0; i < 4; ++i) {
      int row = w * 32 + i * 8 + (lane >> 3);
      const u16* sa = A + (size_t)(rbase + row) * K + kt * 64 + col8;
      GLOAD_LDS16(sa, lsA + (w * 32 + i * 8) * 64 + lane * 8);
      const u16* sb = BT + (size_t)(nbase + row) * K + kt * 64 + col8;
      GLOAD_LDS16(sb, lsB + (w * 32 + i * 8) * 64 + lane * 8);
    }
    __syncthreads();
#pragma unroll
    for (int kk = 0; kk < 2; ++kk) {
      short8 af[4], bfr[4];
#pragma unroll
      for (int m = 0; m < 4; ++m)
        af[m] = *(const short8*)&lsA[(wr * 64 + m * 16 + l15) * 64 + kk * 32 + lg * 8];
#pragma unroll
      for (int n = 0; n < 4; ++n)
        bfr[n] = *(const short8*)&lsB[(wc * 64 + n * 16 + l15) * 64 + kk * 32 + lg * 8];
#pragma unroll
      for (int m = 0; m < 4; ++m)
#pragma unroll
        for (int n = 0; n < 4; ++n)
          acc[m][n] = MFMA16(af[m], bfr[n], acc[m][n], 0, 0, 0);
    }
    __syncthreads();
  }
  const int r0 = rbase + wr * 64;
  const int c0 = nbase + wc * 64;
  if (z == 4) {
    float* out = (float*)dstbase;
#pragma unroll
    for (int m = 0; m < 4; ++m)
#pragma unroll
      for (int n = 0; n < 4; ++n)
#pragma unroll
        for (int i = 0; i < 4; ++i) {
          int r = r0 + m * 16 + lg * 4 + i;
          int c = c0 + n * 16 + l15;
          out[(size_t)r * 1024 + c] = acc[m][n][i] + bvec[c];
        }
  } else {
    u16* dq = (u16*)dstbase + (size_t)z * 4096 * 1024;
#pragma unroll
    for (int m = 0; m < 4; ++m)
#pragma unroll
      for (int n = 0; n < 4; ++n)
#pragma unroll
        for (int i = 0; i < 4; ++i) {
          int r = r0 + m * 16 + lg * 4 + i;
          int c = c0 + n * 16 + l15;
          float v = acc[m][n][i];
          if (z == 0) v *= 0.125f;                                   // q / sqrt(64)
          else if (z == 3) v = 1.f / (1.f + __expf(-(v + bvec[c]))); // sigmoid gate
          dq[(size_t)r * 1024 + c] = f2bf(v);
        }
  }
}

// ---------------- flash attention v19: 1024 small blocks, 2 blocks/CU ----------------
// R15's proven concurrency (512 concurrent barrier groups -> bias 2.5 TB/s) without
// split-K overheads: QBLK=64, 256 thr (4 waves x 16q), one batch/block, LDS 64.5KB ->
// 2 blocks/CU. XCD remap bid=qt*32+h*2+bb keeps K/V sharers on one XCD (R16 lesson).
// R18 bias path (coalesced loads -> bf16 -> LDS) and asm-only depth-2 vmcnt pipeline.
__global__ __launch_bounds__(256, 2) void attn_kernel(
    const u16* __restrict__ qws, const u16* __restrict__ kws,
    const u16* __restrict__ vt, const u16* __restrict__ gws,
    const float* __restrict__ bias, const float* __restrict__ mask,
    u16* __restrict__ og) {
  const int tid = threadIdx.x;
  const int lane = tid & 63;
  const int w = tid >> 6;            // wave 0..3, owns q rows qt*64 + w*16 .. +15
  const int l15 = lane & 15, lg = lane >> 4;
  const int bx = blockIdx.x;         // bid = qt*32 + h*2 + bb (qt-sharers same XCD)
  const int qt = bx >> 5;            // 0..31 (QBLK=64)
  const int rem = bx & 31;
  const int h = rem >> 1;            // 0..15
  const int bb = rem & 1;            // batch
  const int kb0 = ((h << 1) | (qt >> 4)) & 31;   // per-block window phase

#define KWIN(KB) (((KB) + kb0) & 31)

  __shared__ __align__(16) u16 ring[2][8192];   // [slot][K 64x64 swz | V 64x64 swz]
  __shared__ __align__(16) u16 lsB[2][4608];    // [slot][64 q][stride 72] bf16 bias
  __shared__ __align__(16) u16 lsP[4][1152];    // per-wave P [16 q][stride 72]
  __shared__ __align__(16) u16 lsM[2048];       // additive mask bf16 (own batch)

  const float* bias_base = bias + ((size_t)h * 2048 + qt * 64) * 2048;
  const u16* k_base = kws + (size_t)(bb * 2048) * 1024 + h * 64;
  const u16* vt_base = vt + (size_t)((bb * 16 + h) * 64) * 2048;

  // ---- one-time: mask (own batch) -> additive bf16 LDS (256 thr x 8)
  {
    float4 m0 = *(const float4*)(mask + bb * 2048 + tid * 8);
    float4 m1 = *(const float4*)(mask + bb * 2048 + tid * 8 + 4);
    short8 mm;
    mm[0] = (short)f2bf((m0.x - 1.f) * 1e9f); mm[1] = (short)f2bf((m0.y - 1.f) * 1e9f);
    mm[2] = (short)f2bf((m0.z - 1.f) * 1e9f); mm[3] = (short)f2bf((m0.w - 1.f) * 1e9f);
    mm[4] = (short)f2bf((m1.x - 1.f) * 1e9f); mm[5] = (short)f2bf((m1.y - 1.f) * 1e9f);
    mm[6] = (short)f2bf((m1.z - 1.f) * 1e9f); mm[7] = (short)f2bf((m1.w - 1.f) * 1e9f);
    *(short8*)&lsM[tid * 8] = mm;
  }

  // ---- Q fragments (one 16q subtile x 2 c-halves); force-materialize, drain VMEM
  const size_t qrow = (size_t)(bb * 2048 + qt * 64 + w * 16 + l15) * 1024 + h * 64;
  short8 qf0 = *(const short8*)(qws + qrow + lg * 8);
  short8 qf1 = *(const short8*)(qws + qrow + 32 + lg * 8);
  asm volatile("" :: "v"(qf0), "v"(qf1));
  asm volatile("s_waitcnt vmcnt(0)" ::: "memory");
  __builtin_amdgcn_sched_barrier(0);

  f32x4 O[4] = {};                  // O[cf] : c=cf*16+lg*4+i, q=l15
  float lacc = 0.f;                 // per-lane partial softmax denominator
  // two KV staging sets (K0,K1,V0,V1) and two bias staging sets (4 x f32x4)
  f32x4 kX0, kX1, vX0, vX1, kY0, kY1, vY0, vY1;
  f32x4 bX0, bX1, bX2, bX3, bY0, bY1, bY2, bY3;

// K: row r_=t>>2, chunks cg_ and 4+cg_ (each 16B; 4 lanes/row contiguous 64B).
// V: same shape from VT.
#define STAGE_ISSUE(K0, K1, V0, V1, KB) {                                           \
    int kw_ = KWIN(KB);                                                             \
    int r_ = tid >> 2, cg_ = tid & 3;                                               \
    const u16* kp_ = k_base + (size_t)(kw_ * 64 + r_) * 1024 + cg_ * 8;             \
    const u16* vp_ = vt_base + (size_t)r_ * 2048 + kw_ * 64 + cg_ * 8;              \
    asm volatile("global_load_dwordx4 %0, %1, off" : "=v"(K0) : "v"(kp_));          \
    asm volatile("global_load_dwordx4 %0, %1, off" : "=v"(K1) : "v"(kp_ + 32));     \
    asm volatile("global_load_dwordx4 %0, %1, off" : "=v"(V0) : "v"(vp_));          \
    asm volatile("global_load_dwordx4 %0, %1, off" : "=v"(V1) : "v"(vp_ + 32));     \
  }

// granule g of row r at LDS position g^(r&7); K0->granule cg_, K1->granule 4+cg_
#define STAGE_WRITE(SLOT, K0, K1, V0, V1) {                                         \
    int r_ = tid >> 2, cg_ = tid & 3;                                               \
    int d0_ = (r_ * 8 + (cg_ ^ (r_ & 7))) * 8;                                      \
    int d1_ = (r_ * 8 + ((4 + cg_) ^ (r_ & 7))) * 8;                                \
    *(f32x4*)&ring[SLOT][d0_] = K0;                                                 \
    *(f32x4*)&ring[SLOT][d1_] = K1;                                                 \
    *(f32x4*)&ring[SLOT][4096 + d0_] = V0;                                          \
    *(f32x4*)&ring[SLOT][4096 + d1_] = V1;                                          \
  }

// coalesced bias: thread t -> row t>>2, cols (t&3)*4 + {0,16,32,48}; per instruction
// the 4 lanes of a row cover one contiguous 64B line.
#define BIAS_ISSUE(R0, R1, R2, R3, KB) {                                            \
    const float* bp_ = bias_base + (size_t)(tid >> 2) * 2048 + KWIN(KB) * 64 +      \
                       (tid & 3) * 4;                                               \
    asm volatile("global_load_dwordx4 %0, %1, off" : "=v"(R0) : "v"(bp_));          \
    asm volatile("global_load_dwordx4 %0, %1, off" : "=v"(R1) : "v"(bp_ + 16));     \
    asm volatile("global_load_dwordx4 %0, %1, off" : "=v"(R2) : "v"(bp_ + 32));     \
    asm volatile("global_load_dwordx4 %0, %1, off" : "=v"(R3) : "v"(bp_ + 48));     \
  }

#define BIAS_WRITE(SLOT, R0, R1, R2, R3) {                                          \
    int row_ = tid >> 2, c0_ = (tid & 3) * 4;                                       \
    u16* d_ = &lsB[SLOT][row_ * 72 + c0_];                                          \
    short4v p0_, p1_, p2_, p3_;                                                     \
    _Pragma("unroll") for (int i = 0; i < 4; ++i) {                                 \
      p0_[i] = (short)f2bf_rn(R0[i]); p1_[i] = (short)f2bf_rn(R1[i]);               \
      p2_[i] = (short)f2bf_rn(R2[i]); p3_[i] = (short)f2bf_rn(R3[i]);               \
    }                                                                               \
    *(short4v*)&d_[0] = p0_;  *(short4v*)&d_[16] = p1_;                             \
    *(short4v*)&d_[32] = p2_; *(short4v*)&d_[48] = p3_;                             \
  }

#define COMPUTE(SLOT, KB) {                                                         \
    const u16* Kc_ = &ring[SLOT][0];                                                \
    const u16* Vc_ = &ring[SLOT][4096];                                             \
    f32x4 s_[4];                                                                    \
    _Pragma("unroll") for (int kt = 0; kt < 4; ++kt) {                              \
      int krow_ = kt * 16 + l15;                                                    \
      int sw_ = krow_ & 7;                                                          \
      short8 kfa_ = *(const short8*)&Kc_[(krow_ * 8 + (lg ^ sw_)) * 8];             \
      short8 kfb_ = *(const short8*)&Kc_[(krow_ * 8 + ((4 + lg) ^ sw_)) * 8];       \
      short4v mk_ = *(const short4v*)&lsM[KWIN(KB) * 64 + kt * 16 + lg * 4];        \
      short4v bv_ = *(const short4v*)&lsB[SLOT][(w * 16 + l15) * 72 + kt * 16 + lg * 4]; \
      f32x4 ci_;                                                                    \
      _Pragma("unroll") for (int i = 0; i < 4; ++i)                                 \
        ci_[i] = bf2f((u16)bv_[i]) + bf2f((u16)mk_[i]);                             \
      s_[kt] = MFMA16(kfa_, qf0, ci_, 0, 0, 0);                                     \
      s_[kt] = MFMA16(kfb_, qf1, s_[kt], 0, 0, 0);                                  \
    }                                                                               \
    _Pragma("unroll") for (int kt = 0; kt < 4; ++kt) {                              \
      short4v p_;                                                                   \
      _Pragma("unroll") for (int i = 0; i < 4; ++i) {                               \
        float e_ = __expf(s_[kt][i]); lacc += e_; p_[i] = (short)f2bf_rn(e_);       \
      }                                                                             \
      *(short4v*)&lsP[w][l15 * 72 + kt * 16 + lg * 4] = p_;                         \
    }                                                                               \
    short8 pf0_ = *(const short8*)&lsP[w][l15 * 72 + lg * 8];                       \
    short8 pf1_ = *(const short8*)&lsP[w][l15 * 72 + 32 + lg * 8];                  \
    _Pragma("unroll") for (int cf = 0; cf < 4; ++cf) {                              \
      int c_ = cf * 16 + l15;                                                       \
      int sw_ = c_ & 7;                                                             \
      short8 vf0_ = *(const short8*)&Vc_[(c_ * 8 + (lg ^ sw_)) * 8];                \
      short8 vf1_ = *(const short8*)&Vc_[(c_ * 8 + ((4 + lg) ^ sw_)) * 8];          \
      O[cf] = MFMA16(vf0_, pf0_, O[cf], 0, 0, 0);                                   \
      O[cf] = MFMA16(vf1_, pf1_, O[cf], 0, 0, 0);                                   \
    } }

// body KB: issue set(KB+2) {4 KV + 4 bias}; compute body KB from slot KB&1;
// counted wait drains set(KB+1); publish KV+bias(KB+1) into slot (KB+1)&1; barrier.
#define BODY(KB, N, ISK0, ISK1, ISV0, ISV1, IB0, IB1, IB2, IB3,                     \
             WRK0, WRK1, WRV0, WRV1, WB0, WB1, WB2, WB3) {                          \
    if ((KB) + 2 < 32) {                                                            \
      STAGE_ISSUE(ISK0, ISK1, ISV0, ISV1, (KB) + 2);                                \
      BIAS_ISSUE(IB0, IB1, IB2, IB3, (KB) + 2);                                     \
    }                                                                               \
    COMPUTE((KB) & 1, KB);                                                          \
    asm volatile("s_waitcnt vmcnt(" #N ")" ::: "memory");                           \
    __builtin_amdgcn_sched_barrier(0);                                              \
    if ((KB) + 1 < 32) {                                                            \
      STAGE_WRITE(((KB) + 1) & 1, WRK0, WRK1, WRV0, WRV1);                          \
      BIAS_WRITE(((KB) + 1) & 1, WB0, WB1, WB2, WB3);                               \
      asm volatile("s_waitcnt lgkmcnt(0)" ::: "memory");                            \
      __builtin_amdgcn_sched_barrier(0);                                            \
      __builtin_amdgcn_s_barrier();                                                 \
    } }

  // ---- prologue: set0 -> X/XB, set1 -> Y/YB; drain set0; publish slot0
  STAGE_ISSUE(kX0, kX1, vX0, vX1, 0);
  BIAS_ISSUE(bX0, bX1, bX2, bX3, 0);
  STAGE_ISSUE(kY0, kY1, vY0, vY1, 1);
  BIAS_ISSUE(bY0, bY1, bY2, bY3, 1);
  asm volatile("s_waitcnt vmcnt(8)" ::: "memory");    // set 0 landed; set 1 in flight
  __builtin_amdgcn_sched_barrier(0);
  STAGE_WRITE(0, kX0, kX1, vX0, vX1);
  BIAS_WRITE(0, bX0, bX1, bX2, bX3);
  asm volatile("s_waitcnt lgkmcnt(0)" ::: "memory");  // slot0 + lsM published
  __builtin_amdgcn_sched_barrier(0);
  __builtin_amdgcn_s_barrier();

  for (int kb2 = 0; kb2 < 30; kb2 += 2) {
    BODY(kb2,     8, kX0, kX1, vX0, vX1, bX0, bX1, bX2, bX3,
         kY0, kY1, vY0, vY1, bY0, bY1, bY2, bY3);
    BODY(kb2 + 1, 8, kY0, kY1, vY0, vY1, bY0, bY1, bY2, bY3,
         kX0, kX1, vX0, vX1, bX0, bX1, bX2, bX3);
  }
  BODY(30, 0, kX0, kX1, vX0, vX1, bX0, bX1, bX2, bX3,
       kY0, kY1, vY0, vY1, bY0, bY1, bY2, bY3);
  BODY(31, 0, kY0, kY1, vY0, vY1, bY0, bY1, bY2, bY3,
       kX0, kX1, vX0, vX1, bX0, bX1, bX2, bX3);

  // ---- epilogue: reduce l across lg groups, gate, store bf16
  lacc += __shfl_xor(lacc, 16);
  lacc += __shfl_xor(lacc, 32);
  {
    float inv = 1.f / lacc;
#pragma unroll
    for (int cf = 0; cf < 4; ++cf) {
      short4v ga = *(const short4v*)(gws + qrow + cf * 16 + lg * 4);
      short4v oa;
#pragma unroll
      for (int i = 0; i < 4; ++i)
        oa[i] = (short)f2bf_rn(O[cf][i] * inv * bf2f((u16)ga[i]));
      *(short4v*)(og + qrow + cf * 16 + lg * 4) = oa;
    }
  }
#undef STAGE_ISSUE
#undef STAGE_WRITE
#undef BIAS_ISSUE
#undef BIAS_WRITE
#undef COMPUTE
#undef BODY
#undef KWIN
}

extern "C" void kernel_launch(void* const* d_in, const int* in_sizes, int n_in,
                              void* d_out, int out_size, void* d_ws, size_t ws_size,
                              hipStream_t stream) {
  const float* x    = (const float*)d_in[0];
  const float* mask = (const float*)d_in[1];
  const float* bias = (const float*)d_in[2];
  const float* wq   = (const float*)d_in[3];
  const float* wk   = (const float*)d_in[4];
  const float* wv   = (const float*)d_in[5];
  const float* wg   = (const float*)d_in[6];
  const float* bg   = (const float*)d_in[7];
  const float* wo   = (const float*)d_in[8];
  const float* bo   = (const float*)d_in[9];
  float* out = (float*)d_out;

  char* ws = (char*)d_ws;
  const size_t MB = 1ull << 20;
  u16* xb   = (u16*)(ws + 0);        // 4096x1024 bf16 input          (8 MB)
  u16* wt   = (u16*)(ws + 8 * MB);   // 4x WT [1024][1024] bf16       (8 MB)
  u16* wot  = (u16*)(ws + 16 * MB);  // WOT [1024][1024] bf16         (2 MB)
  u16* proj = (u16*)(ws + 18 * MB);  // q,k,v,g each 4096x1024 bf16   (32 MB)
  u16* vtp  = (u16*)(ws + 50 * MB);  // VT [b,h,c,s] bf16             (8 MB)
  u16* og   = (u16*)(ws + 58 * MB);  // gated attention out bf16      (8 MB)
  const size_t PSZ = (size_t)4096 * 1024;

  convert_bf16_kernel<<<2048, 256, 0, stream>>>(x, xb, 4096 * 1024);

  transpose_w64_4<<<dim3(16, 16, 4), 256, 0, stream>>>(wq, wk, wv, wg, wt);
  transpose_w64<<<dim3(16, 16), 256, 0, stream>>>(wo, wot, 1024, 1024);

  gemm_bt128<<<dim3(32, 8, 4), 256, 0, stream>>>(xb, wt, (void*)proj, bg, -1);

  transpose_v64<<<dim3(32, 32), 256, 0, stream>>>(proj + 2 * PSZ, vtp);

  attn_kernel<<<1024, 256, 0, stream>>>(proj, proj + PSZ, vtp, proj + 3 * PSZ,
                                        bias, mask, og);

  gemm_bt128<<<dim3(32, 8, 1), 256, 0, stream>>>(og, wot, (void*)out, bo, 4);
}

// Round 20
// 188.212 us; speedup vs baseline: 1.1725x; 1.1725x over previous
//
#include <hip/hip_runtime.h>
#include <hip/hip_bf16.h>
#include <stdint.h>

typedef unsigned short u16;
typedef __attribute__((ext_vector_type(8))) short short8;
typedef __attribute__((ext_vector_type(4))) short short4v;
typedef __attribute__((ext_vector_type(4))) float f32x4;

#define MFMA16 __builtin_amdgcn_mfma_f32_16x16x32_bf16

#define GLOAD_LDS16(gsrc, ldst) \
  __builtin_amdgcn_global_load_lds((const __attribute__((address_space(1))) void*)(gsrc), \
                                   (__attribute__((address_space(3))) void*)(ldst), 16, 0, 0)

__device__ __forceinline__ u16 f2bf(float x) {
  union { float f; uint32_t u; } v; v.f = x;
  uint32_t r = v.u + 0x7FFFu + ((v.u >> 16) & 1u);
  return (u16)(r >> 16);
}
__device__ __forceinline__ u16 f2bf_rn(float x) {
  __hip_bfloat16 h = __float2bfloat16(x);
  return *reinterpret_cast<u16*>(&h);
}
__device__ __forceinline__ float bf2f(u16 b) {
  union { uint32_t u; float f; } v; v.u = ((uint32_t)b) << 16;
  return v.f;
}

// ---------------- convert f32 -> bf16 (elementwise, vectorized) ----------------
__global__ __launch_bounds__(256) void convert_bf16_kernel(
    const float* __restrict__ in, u16* __restrict__ out, int n) {
  int i = (blockIdx.x * 256 + threadIdx.x) * 8;
  if (i >= n) return;
  float4 a = *(const float4*)(in + i);
  float4 b = *(const float4*)(in + i + 4);
  short8 t;
  t[0] = (short)f2bf(a.x); t[1] = (short)f2bf(a.y);
  t[2] = (short)f2bf(a.z); t[3] = (short)f2bf(a.w);
  t[4] = (short)f2bf(b.x); t[5] = (short)f2bf(b.y);
  t[6] = (short)f2bf(b.z); t[7] = (short)f2bf(b.w);
  *(short8*)(out + i) = t;
}

// ---------------- transpose 5 weights f32 [K][N] -> bf16 [N][K], z selects W ----------------
// z=0..3 -> wq/wk/wv/wg into WT[z]; z=4 -> wo into WOT.
__global__ __launch_bounds__(256) void transpose_w64_5(
    const float* __restrict__ w0, const float* __restrict__ w1,
    const float* __restrict__ w2, const float* __restrict__ w3,
    const float* __restrict__ w4, u16* __restrict__ WT, u16* __restrict__ WOT) {
  __shared__ float tile[64][68];
  const int t = threadIdx.x;
  const int z = blockIdx.z;
  const float* W = (z == 0) ? w0 : (z == 1) ? w1 : (z == 2) ? w2 : (z == 3) ? w3 : w4;
  u16* dst_base = (z == 4) ? WOT : WT + (size_t)z * 1024 * 1024;
  const int k0 = blockIdx.x * 64, n0 = blockIdx.y * 64;
  {
    int r = t >> 2, c0 = (t & 3) * 16;
    const float* src = W + (size_t)(k0 + r) * 1024 + n0 + c0;
#pragma unroll
    for (int j = 0; j < 16; j += 4) {
      float4 v = *(const float4*)(src + j);
      tile[r][c0 + j + 0] = v.x; tile[r][c0 + j + 1] = v.y;
      tile[r][c0 + j + 2] = v.z; tile[r][c0 + j + 3] = v.w;
    }
  }
  __syncthreads();
  {
    int n = t >> 2, kq = (t & 3) * 16;
    short8 t0, t1;
#pragma unroll
    for (int j = 0; j < 8; ++j)  t0[j] = (short)f2bf(tile[kq + j][n]);
#pragma unroll
    for (int j = 0; j < 8; ++j)  t1[j] = (short)f2bf(tile[kq + 8 + j][n]);
    u16* dst = dst_base + (size_t)(n0 + n) * 1024 + k0 + kq;
    *(short8*)dst = t0;
    *(short8*)(dst + 8) = t1;
  }
}

// ---------------- transpose V bf16 [b*2048+s][h*64+c] -> VT [(b*16+h)*64+c][s] ----------------
__global__ __launch_bounds__(256) void transpose_v64(
    const u16* __restrict__ vin, u16* __restrict__ vout) {
  __shared__ u16 tile[64][80];
  const int t = threadIdx.x;
  const int s0 = blockIdx.x * 64;
  const int bh = blockIdx.y;  // b*16+h
  const int b = bh >> 4, h = bh & 15;
  {
    int r = t >> 2, c0 = (t & 3) * 16;
    const u16* src = vin + (size_t)(b * 2048 + s0 + r) * 1024 + h * 64 + c0;
    *(short8*)&tile[r][c0] = *(const short8*)src;
    *(short8*)&tile[r][c0 + 8] = *(const short8*)(src + 8);
  }
  __syncthreads();
  {
    int c = t >> 2, s4 = (t & 3) * 16;
    short8 t0, t1;
#pragma unroll
    for (int j = 0; j < 8; ++j) t0[j] = (short)tile[s4 + j][c];
#pragma unroll
    for (int j = 0; j < 8; ++j) t1[j] = (short)tile[s4 + 8 + j][c];
    u16* dst = vout + (size_t)(bh * 64 + c) * 2048 + s0 + s4;
    *(short8*)dst = t0;
    *(short8*)(dst + 8) = t1;
  }
}

// ---------------- GEMM: D[r][n] = sum_k A[r][k]*BT[n][k], m97-style 128x128/BK=64 ----------------
__global__ __launch_bounds__(256) void gemm_bt128(
    const u16* __restrict__ A, const u16* __restrict__ BTbase,
    void* __restrict__ dstbase, const float* __restrict__ bvec, int mode) {
  const int K = 1024;
  const int tid = threadIdx.x, lane = tid & 63, w = tid >> 6;
  const int wr = w >> 1, wc = w & 1;
  const int l15 = lane & 15, lg = lane >> 4;
  const int z = (mode < 0) ? (int)blockIdx.z : mode;
  const u16* BT = (mode < 0) ? BTbase + (size_t)z * 1024 * 1024 : BTbase;
  const int rbase = blockIdx.x * 128;
  const int nbase = blockIdx.y * 128;
  __shared__ u16 lsA[128 * 64];
  __shared__ u16 lsB[128 * 64];
  f32x4 acc[4][4] = {};
  const int col8 = (lane & 7) * 8;
  for (int kt = 0; kt < K / 64; ++kt) {
#pragma unroll
    for (int i = 0; i < 4; ++i) {
      int row = w * 32 + i * 8 + (lane >> 3);
      const u16* sa = A + (size_t)(rbase + row) * K + kt * 64 + col8;
      GLOAD_LDS16(sa, lsA + (w * 32 + i * 8) * 64 + lane * 8);
      const u16* sb = BT + (size_t)(nbase + row) * K + kt * 64 + col8;
      GLOAD_LDS16(sb, lsB + (w * 32 + i * 8) * 64 + lane * 8);
    }
    __syncthreads();
#pragma unroll
    for (int kk = 0; kk < 2; ++kk) {
      short8 af[4], bfr[4];
#pragma unroll
      for (int m = 0; m < 4; ++m)
        af[m] = *(const short8*)&lsA[(wr * 64 + m * 16 + l15) * 64 + kk * 32 + lg * 8];
#pragma unroll
      for (int n = 0; n < 4; ++n)
        bfr[n] = *(const short8*)&lsB[(wc * 64 + n * 16 + l15) * 64 + kk * 32 + lg * 8];
#pragma unroll
      for (int m = 0; m < 4; ++m)
#pragma unroll
        for (int n = 0; n < 4; ++n)
          acc[m][n] = MFMA16(af[m], bfr[n], acc[m][n], 0, 0, 0);
    }
    __syncthreads();
  }
  const int r0 = rbase + wr * 64;
  const int c0 = nbase + wc * 64;
  if (z == 4) {
    float* out = (float*)dstbase;
#pragma unroll
    for (int m = 0; m < 4; ++m)
#pragma unroll
      for (int n = 0; n < 4; ++n)
#pragma unroll
        for (int i = 0; i < 4; ++i) {
          int r = r0 + m * 16 + lg * 4 + i;
          int c = c0 + n * 16 + l15;
          out[(size_t)r * 1024 + c] = acc[m][n][i] + bvec[c];
        }
  } else {
    u16* dq = (u16*)dstbase + (size_t)z * 4096 * 1024;
#pragma unroll
    for (int m = 0; m < 4; ++m)
#pragma unroll
      for (int n = 0; n < 4; ++n)
#pragma unroll
        for (int i = 0; i < 4; ++i) {
          int r = r0 + m * 16 + lg * 4 + i;
          int c = c0 + n * 16 + l15;
          float v = acc[m][n][i];
          if (z == 0) v *= 0.125f;                                   // q / sqrt(64)
          else if (z == 3) v = 1.f / (1.f + __expf(-(v + bvec[c]))); // sigmoid gate
          dq[(size_t)r * 1024 + c] = f2bf(v);
        }
  }
}

// ---------------- flash attention v18 (best passing): coalesced LDS-staged bias ----------------
// Batch-merged 512-thr blocks (bias read ONCE per (qt,h)); reg-staged K/V; coalesced bias
// loads (per instruction, 4 lanes of a row cover one contiguous 64B line) -> bf16 ->
// stride-72 LDS tile; asm-only depth-2 pipeline, vmcnt(8) steady, one barrier/body.
__global__ __launch_bounds__(512, 2) void attn_kernel(
    const u16* __restrict__ qws, const u16* __restrict__ kws,
    const u16* __restrict__ vt, const u16* __restrict__ gws,
    const float* __restrict__ bias, const float* __restrict__ mask,
    u16* __restrict__ og) {
  const int tid = threadIdx.x;
  const int lane = tid & 63;
  const int w = tid >> 6;            // wave 0..7
  const int bb = w >> 2;             // batch
  const int ws = w & 3;              // q sub-tile (32 rows)
  const int l15 = lane & 15, lg = lane >> 4;
  const int qt = blockIdx.x;         // 0..15
  const int h = blockIdx.y;
  const int kb0 = ((h << 1) | (qt >> 3)) & 31;   // per-block window phase

#define KWIN(KB) (((KB) + kb0) & 31)

  __shared__ __align__(16) u16 ring[2][16384];  // [slot][K0|V0|K1|V1] 4096 u16 each, swz
  __shared__ __align__(16) u16 lsB[2][9216];    // [slot][128 q][stride 72] bf16 bias
  __shared__ __align__(16) u16 lsP[8][2304];    // per-wave P [32 q][stride 72]
  __shared__ __align__(16) u16 lsM[4096];       // additive mask bf16, both batches

  const float* bias_base = bias + ((size_t)h * 2048 + qt * 128) * 2048;
  const u16* k_base0 = kws + (size_t)h * 64;
  const u16* k_base1 = kws + (size_t)2048 * 1024 + h * 64;
  const u16* vt_base0 = vt + (size_t)(h * 64) * 2048;
  const u16* vt_base1 = vt + (size_t)((16 + h) * 64) * 2048;

  // ---- one-time: mask (both batches) -> additive bf16 LDS (512 thr x 8)
  {
    float4 m0 = *(const float4*)(mask + tid * 8);
    float4 m1 = *(const float4*)(mask + tid * 8 + 4);
    short8 mm;
    mm[0] = (short)f2bf((m0.x - 1.f) * 1e9f); mm[1] = (short)f2bf((m0.y - 1.f) * 1e9f);
    mm[2] = (short)f2bf((m0.z - 1.f) * 1e9f); mm[3] = (short)f2bf((m0.w - 1.f) * 1e9f);
    mm[4] = (short)f2bf((m1.x - 1.f) * 1e9f); mm[5] = (short)f2bf((m1.y - 1.f) * 1e9f);
    mm[6] = (short)f2bf((m1.z - 1.f) * 1e9f); mm[7] = (short)f2bf((m1.w - 1.f) * 1e9f);
    *(short8*)&lsM[tid * 8] = mm;
  }

  // ---- Q fragments (own batch); force-materialize, then drain VMEM
  const size_t qrow0 = (size_t)(bb * 2048 + qt * 128 + ws * 32 + l15) * 1024 + h * 64;
  const size_t qrow1 = qrow0 + 16 * 1024;
  short8 qf00 = *(const short8*)(qws + qrow0 + lg * 8);
  short8 qf01 = *(const short8*)(qws + qrow0 + 32 + lg * 8);
  short8 qf10 = *(const short8*)(qws + qrow1 + lg * 8);
  short8 qf11 = *(const short8*)(qws + qrow1 + 32 + lg * 8);
  asm volatile("" :: "v"(qf00), "v"(qf01), "v"(qf10), "v"(qf11));
  asm volatile("s_waitcnt vmcnt(0)" ::: "memory");   // all tracked VMEM drained
  __builtin_amdgcn_sched_barrier(0);

  f32x4 O[2][4] = {};               // O[qa][cf] : c=cf*16+lg*4+i, q=qa*16+l15
  float lacc0 = 0.f, lacc1 = 0.f;   // per-lane partial softmax denominators
  f32x4 kX0, kX1, vX0, vX1, kY0, kY1, vY0, vY1;
  f32x4 bX0, bX1, bX2, bX3, bY0, bY1, bY2, bY3;

// asm global loads: each thread loads one 16B chunk of K and V for BOTH batches
#define STAGE_ISSUE(K0, K1, V0, V1, KB) {                                           \
    int kw_ = KWIN(KB);                                                             \
    int r_ = tid >> 3, cg_ = tid & 7;                                               \
    const u16* kp0 = k_base0 + (size_t)(kw_ * 64 + r_) * 1024 + cg_ * 8;            \
    const u16* kp1 = k_base1 + (size_t)(kw_ * 64 + r_) * 1024 + cg_ * 8;            \
    const u16* vp0 = vt_base0 + (size_t)r_ * 2048 + kw_ * 64 + cg_ * 8;             \
    const u16* vp1 = vt_base1 + (size_t)r_ * 2048 + kw_ * 64 + cg_ * 8;             \
    asm volatile("global_load_dwordx4 %0, %1, off" : "=v"(K0) : "v"(kp0));          \
    asm volatile("global_load_dwordx4 %0, %1, off" : "=v"(K1) : "v"(kp1));          \
    asm volatile("global_load_dwordx4 %0, %1, off" : "=v"(V0) : "v"(vp0));          \
    asm volatile("global_load_dwordx4 %0, %1, off" : "=v"(V1) : "v"(vp1));          \
  }

#define STAGE_WRITE(SLOT, K0, K1, V0, V1) {                                         \
    int r_ = tid >> 3, cg_ = tid & 7;                                               \
    int d0_ = (r_ * 8 + (cg_ ^ (r_ & 7))) * 8;                                      \
    *(f32x4*)&ring[SLOT][d0_] = K0;                                                 \
    *(f32x4*)&ring[SLOT][4096 + d0_] = V0;                                          \
    *(f32x4*)&ring[SLOT][8192 + d0_] = K1;                                          \
    *(f32x4*)&ring[SLOT][12288 + d0_] = V1;                                         \
  }

// coalesced bias: thread t covers cols (tid&3)*4 + {0,16,32,48}; per instruction
// the 4 lanes of a row read one contiguous 64B line.
#define BIAS_ISSUE(R0, R1, R2, R3, KB) {                                            \
    const float* bp_ = bias_base + (size_t)(tid >> 2) * 2048 + KWIN(KB) * 64 +      \
                       (tid & 3) * 4;                                               \
    asm volatile("global_load_dwordx4 %0, %1, off" : "=v"(R0) : "v"(bp_));          \
    asm volatile("global_load_dwordx4 %0, %1, off" : "=v"(R1) : "v"(bp_ + 16));     \
    asm volatile("global_load_dwordx4 %0, %1, off" : "=v"(R2) : "v"(bp_ + 32));     \
    asm volatile("global_load_dwordx4 %0, %1, off" : "=v"(R3) : "v"(bp_ + 48));     \
  }

#define BIAS_WRITE(SLOT, R0, R1, R2, R3) {                                          \
    int row_ = tid >> 2, c0_ = (tid & 3) * 4;                                       \
    u16* d_ = &lsB[SLOT][row_ * 72 + c0_];                                          \
    short4v p0_, p1_, p2_, p3_;                                                     \
    _Pragma("unroll") for (int i = 0; i < 4; ++i) {                                 \
      p0_[i] = (short)f2bf_rn(R0[i]); p1_[i] = (short)f2bf_rn(R1[i]);               \
      p2_[i] = (short)f2bf_rn(R2[i]); p3_[i] = (short)f2bf_rn(R3[i]);               \
    }                                                                               \
    *(short4v*)&d_[0] = p0_;  *(short4v*)&d_[16] = p1_;                             \
    *(short4v*)&d_[32] = p2_; *(short4v*)&d_[48] = p3_;                             \
  }

#define COMPUTE(SLOT, KB) {                                                         \
    const u16* Kc_ = &ring[SLOT][bb * 8192];                                        \
    const u16* Vc_ = &ring[SLOT][bb * 8192 + 4096];                                 \
    f32x4 s_[2][4];                                                                 \
    _Pragma("unroll") for (int kt = 0; kt < 4; ++kt) {                              \
      int krow_ = kt * 16 + l15;                                                    \
      int sw_ = krow_ & 7;                                                          \
      short8 kfa_ = *(const short8*)&Kc_[(krow_ * 8 + (lg ^ sw_)) * 8];             \
      short8 kfb_ = *(const short8*)&Kc_[(krow_ * 8 + ((4 + lg) ^ sw_)) * 8];       \
      short4v mk_ = *(const short4v*)&lsM[bb * 2048 + KWIN(KB) * 64 + kt * 16 + lg * 4]; \
      short4v bv0_ = *(const short4v*)&lsB[SLOT][(ws * 32 + l15) * 72 + kt * 16 + lg * 4]; \
      short4v bv1_ = *(const short4v*)&lsB[SLOT][(ws * 32 + 16 + l15) * 72 + kt * 16 + lg * 4]; \
      f32x4 ci0_, ci1_;                                                             \
      _Pragma("unroll") for (int i = 0; i < 4; ++i) {                               \
        float m_ = bf2f((u16)mk_[i]);                                               \
        ci0_[i] = bf2f((u16)bv0_[i]) + m_;                                          \
        ci1_[i] = bf2f((u16)bv1_[i]) + m_;                                          \
      }                                                                             \
      s_[0][kt] = MFMA16(kfa_, qf00, ci0_, 0, 0, 0);                                \
      s_[0][kt] = MFMA16(kfb_, qf01, s_[0][kt], 0, 0, 0);                           \
      s_[1][kt] = MFMA16(kfa_, qf10, ci1_, 0, 0, 0);                                \
      s_[1][kt] = MFMA16(kfb_, qf11, s_[1][kt], 0, 0, 0);                           \
    }                                                                               \
    _Pragma("unroll") for (int kt = 0; kt < 4; ++kt) {                              \
      short4v p0_, p1_;                                                             \
      _Pragma("unroll") for (int i = 0; i < 4; ++i) {                               \
        float e0_ = __expf(s_[0][kt][i]); lacc0 += e0_; p0_[i] = (short)f2bf_rn(e0_); \
        float e1_ = __expf(s_[1][kt][i]); lacc1 += e1_; p1_[i] = (short)f2bf_rn(e1_); \
      }                                                                             \
      *(short4v*)&lsP[w][(l15) * 72 + kt * 16 + lg * 4] = p0_;                      \
      *(short4v*)&lsP[w][(16 + l15) * 72 + kt * 16 + lg * 4] = p1_;                 \
    }                                                                               \
    short8 pf00_ = *(const short8*)&lsP[w][(l15) * 72 + lg * 8];                    \
    short8 pf01_ = *(const short8*)&lsP[w][(l15) * 72 + 32 + lg * 8];               \
    short8 pf10_ = *(const short8*)&lsP[w][(16 + l15) * 72 + lg * 8];               \
    short8 pf11_ = *(const short8*)&lsP[w][(16 + l15) * 72 + 32 + lg * 8];          \
    _Pragma("unroll") for (int cf = 0; cf < 4; ++cf) {                              \
      int c_ = cf * 16 + l15;                                                       \
      int sw_ = c_ & 7;                                                             \
      short8 vf0_ = *(const short8*)&Vc_[(c_ * 8 + (lg ^ sw_)) * 8];                \
      short8 vf1_ = *(const short8*)&Vc_[(c_ * 8 + ((4 + lg) ^ sw_)) * 8];          \
      O[0][cf] = MFMA16(vf0_, pf00_, O[0][cf], 0, 0, 0);                            \
      O[0][cf] = MFMA16(vf1_, pf01_, O[0][cf], 0, 0, 0);                            \
      O[1][cf] = MFMA16(vf0_, pf10_, O[1][cf], 0, 0, 0);                            \
      O[1][cf] = MFMA16(vf1_, pf11_, O[1][cf], 0, 0, 0);                            \
    } }

#define BODY(KB, N, ISK0, ISK1, ISV0, ISV1, IB0, IB1, IB2, IB3,                     \
             WRK0, WRK1, WRV0, WRV1, WB0, WB1, WB2, WB3) {                          \
    if ((KB) + 2 < 32) {                                                            \
      STAGE_ISSUE(ISK0, ISK1, ISV0, ISV1, (KB) + 2);                                \
      BIAS_ISSUE(IB0, IB1, IB2, IB3, (KB) + 2);                                     \
    }                                                                               \
    COMPUTE((KB) & 1, KB);                                                          \
    asm volatile("s_waitcnt vmcnt(" #N ")" ::: "memory");                           \
    __builtin_amdgcn_sched_barrier(0);                                              \
    if ((KB) + 1 < 32) {                                                            \
      STAGE_WRITE(((KB) + 1) & 1, WRK0, WRK1, WRV0, WRV1);                          \
      BIAS_WRITE(((KB) + 1) & 1, WB0, WB1, WB2, WB3);                               \
      asm volatile("s_waitcnt lgkmcnt(0)" ::: "memory");                            \
      __builtin_amdgcn_sched_barrier(0);                                            \
      __builtin_amdgcn_s_barrier();                                                 \
    } }

  // ---- prologue: set0 -> X/XB, set1 -> Y/YB; drain set0; publish slot0
  STAGE_ISSUE(kX0, kX1, vX0, vX1, 0);
  BIAS_ISSUE(bX0, bX1, bX2, bX3, 0);
  STAGE_ISSUE(kY0, kY1, vY0, vY1, 1);
  BIAS_ISSUE(bY0, bY1, bY2, bY3, 1);
  asm volatile("s_waitcnt vmcnt(8)" ::: "memory");    // set 0 landed; set 1 in flight
  __builtin_amdgcn_sched_barrier(0);
  STAGE_WRITE(0, kX0, kX1, vX0, vX1);
  BIAS_WRITE(0, bX0, bX1, bX2, bX3);
  asm volatile("s_waitcnt lgkmcnt(0)" ::: "memory");  // slot0 + lsM published
  __builtin_amdgcn_sched_barrier(0);
  __builtin_amdgcn_s_barrier();

  for (int kb2 = 0; kb2 < 30; kb2 += 2) {
    BODY(kb2,     8, kX0, kX1, vX0, vX1, bX0, bX1, bX2, bX3,
         kY0, kY1, vY0, vY1, bY0, bY1, bY2, bY3);
    BODY(kb2 + 1, 8, kY0, kY1, vY0, vY1, bY0, bY1, bY2, bY3,
         kX0, kX1, vX0, vX1, bX0, bX1, bX2, bX3);
  }
  BODY(30, 0, kX0, kX1, vX0, vX1, bX0, bX1, bX2, bX3,
       kY0, kY1, vY0, vY1, bY0, bY1, bY2, bY3);
  BODY(31, 0, kY0, kY1, vY0, vY1, bY0, bY1, bY2, bY3,
       kX0, kX1, vX0, vX1, bX0, bX1, bX2, bX3);

  // ---- epilogue: reduce l across lg groups, gate, store bf16
  lacc0 += __shfl_xor(lacc0, 16); lacc0 += __shfl_xor(lacc0, 32);
  lacc1 += __shfl_xor(lacc1, 16); lacc1 += __shfl_xor(lacc1, 32);
  {
    float inv0 = 1.f / lacc0, inv1 = 1.f / lacc1;
#pragma unroll
    for (int cf = 0; cf < 4; ++cf) {
      short4v ga = *(const short4v*)(gws + qrow0 + cf * 16 + lg * 4);
      short4v gb = *(const short4v*)(gws + qrow1 + cf * 16 + lg * 4);
      short4v oa, ob;
#pragma unroll
      for (int i = 0; i < 4; ++i) {
        oa[i] = (short)f2bf_rn(O[0][cf][i] * inv0 * bf2f((u16)ga[i]));
        ob[i] = (short)f2bf_rn(O[1][cf][i] * inv1 * bf2f((u16)gb[i]));
      }
      *(short4v*)(og + qrow0 + cf * 16 + lg * 4) = oa;
      *(short4v*)(og + qrow1 + cf * 16 + lg * 4) = ob;
    }
  }
#undef STAGE_ISSUE
#undef STAGE_WRITE
#undef BIAS_ISSUE
#undef BIAS_WRITE
#undef COMPUTE
#undef BODY
#undef KWIN
}

extern "C" void kernel_launch(void* const* d_in, const int* in_sizes, int n_in,
                              void* d_out, int out_size, void* d_ws, size_t ws_size,
                              hipStream_t stream) {
  const float* x    = (const float*)d_in[0];
  const float* mask = (const float*)d_in[1];
  const float* bias = (const float*)d_in[2];
  const float* wq   = (const float*)d_in[3];
  const float* wk   = (const float*)d_in[4];
  const float* wv   = (const float*)d_in[5];
  const float* wg   = (const float*)d_in[6];
  const float* bg   = (const float*)d_in[7];
  const float* wo   = (const float*)d_in[8];
  const float* bo   = (const float*)d_in[9];
  float* out = (float*)d_out;

  char* ws = (char*)d_ws;
  const size_t MB = 1ull << 20;
  u16* xb   = (u16*)(ws + 0);        // 4096x1024 bf16 input          (8 MB)
  u16* wt   = (u16*)(ws + 8 * MB);   // 4x WT [1024][1024] bf16       (8 MB)
  u16* wot  = (u16*)(ws + 16 * MB);  // WOT [1024][1024] bf16         (2 MB)
  u16* proj = (u16*)(ws + 18 * MB);  // q,k,v,g each 4096x1024 bf16   (32 MB)
  u16* vtp  = (u16*)(ws + 50 * MB);  // VT [b,h,c,s] bf16             (8 MB)
  u16* og   = (u16*)(ws + 58 * MB);  // gated attention out bf16      (8 MB)
  const size_t PSZ = (size_t)4096 * 1024;

  convert_bf16_kernel<<<2048, 256, 0, stream>>>(x, xb, 4096 * 1024);

  transpose_w64_5<<<dim3(16, 16, 5), 256, 0, stream>>>(wq, wk, wv, wg, wo, wt, wot);

  gemm_bt128<<<dim3(32, 8, 4), 256, 0, stream>>>(xb, wt, (void*)proj, bg, -1);

  transpose_v64<<<dim3(32, 32), 256, 0, stream>>>(proj + 2 * PSZ, vtp);

  attn_kernel<<<dim3(16, 16), 512, 0, stream>>>(proj, proj + PSZ, vtp, proj + 3 * PSZ,
                                                bias, mask, og);

  gemm_bt128<<<dim3(32, 8, 1), 256, 0, stream>>>(og, wot, (void*)out, bo, 4);
}